// Round 4
// baseline (169.636 us; speedup 1.0000x reference)
//
#include <hip/hip_runtime.h>
#include <hip/hip_bf16.h>
#include <stdint.h>

#define NR   4096
#define DIM  1024
#define NE   8
#define BM   128
#define BN   128
#define GBK  64

typedef __attribute__((ext_vector_type(8))) short  bf16x8;
typedef __attribute__((ext_vector_type(8))) ushort u16x8;
typedef __attribute__((ext_vector_type(4))) float  f32x4;

__device__ __forceinline__ ushort f2bf(float f) {
    union { __hip_bfloat16 h; ushort u; } cv;
    cv.h = __float2bfloat16(f);   // RNE
    return cv.u;
}

__device__ __forceinline__ void gload16(const void* g, void* l) {
    __builtin_amdgcn_global_load_lds(
        (const __attribute__((address_space(1))) unsigned int*)g,
        (__attribute__((address_space(3))) unsigned int*)l, 16, 0, 0);
}

// ---------------- convert+transpose We: [e][k][c] f32 -> WeT [e][c][k] bf16 ---
// blocks 0/1 additionally transpose Wg/Wn -> WT[16][1024] f32; block 0 zeroes cnt
__global__ __launch_bounds__(256)
void conv_we(const float* __restrict__ We, ushort* __restrict__ WeT,
             const float* __restrict__ Wg, const float* __restrict__ Wn,
             float* __restrict__ WT, int* __restrict__ cnt) {
    if (blockIdx.x == 0 && threadIdx.x < 2 * NE) cnt[threadIdx.x] = 0;
    if (blockIdx.x < 2) {
        const float* Ws = (blockIdx.x == 0) ? Wg : Wn;
        float* dstT = WT + (size_t)blockIdx.x * 8 * DIM;
#pragma unroll
        for (int i = 0; i < 8; ++i) {
            int idx = i * 256 + threadIdx.x;     // 2048 float4 units
            int k = idx >> 1, e4 = (idx & 1) * 4;
            float4 v = *(const float4*)(Ws + (size_t)k * NE + e4);
            dstT[(size_t)(e4 + 0) * DIM + k] = v.x;
            dstT[(size_t)(e4 + 1) * DIM + k] = v.y;
            dstT[(size_t)(e4 + 2) * DIM + k] = v.z;
            dstT[(size_t)(e4 + 3) * DIM + k] = v.w;
        }
    }
    const int b  = blockIdx.x;              // e*256 + kt*16 + ct
    const int e  = b >> 8, kt = (b >> 4) & 15, ct = b & 15;
    __shared__ float T[64][68];
    const float* src = We + ((size_t)e * DIM + (size_t)kt * 64) * DIM + ct * 64;
#pragma unroll
    for (int j = 0; j < 4; ++j) {
        int idx = threadIdx.x + j * 256;
        int r = idx >> 4, c4 = idx & 15;
        float4 v = *(const float4*)(src + (size_t)r * DIM + c4 * 4);
        *(float4*)&T[r][c4 * 4] = v;
    }
    __syncthreads();
    ushort* dst = WeT + ((size_t)e * DIM + (size_t)ct * 64) * DIM + kt * 64;
#pragma unroll
    for (int j = 0; j < 2; ++j) {
        int u = threadIdx.x + j * 256;
        int c = u >> 3, ch = u & 7;
        ushort tmp[8];
#pragma unroll
        for (int q = 0; q < 8; ++q) tmp[q] = f2bf(T[ch * 8 + q][c]);
        *(u16x8*)(dst + (size_t)c * DIM + ch * 8) = *(u16x8*)tmp;
    }
}

// ---------------- gating v4: one wave per row, W from L2, LDS-transpose reduce
__global__ __launch_bounds__(256, 4)
void gate_v4(const float* __restrict__ x, const float* __restrict__ noise,
             const float* __restrict__ WT, ushort* __restrict__ xbf,
             int* __restrict__ cnt, int* __restrict__ idxl, float* __restrict__ wl) {
    __shared__ float red[4][64][17];
    const int tid = threadIdx.x, w = tid >> 6, l = tid & 63;
    const int row = blockIdx.x * 4 + w;
    const float* xr = x + (size_t)row * DIM;

    float4 xv[4];
#pragma unroll
    for (int q = 0; q < 4; ++q) xv[q] = *(const float4*)(xr + q * 256 + l * 4);
#pragma unroll
    for (int q = 0; q < 4; ++q) {
        ushort4 xb;
        xb.x = f2bf(xv[q].x); xb.y = f2bf(xv[q].y);
        xb.z = f2bf(xv[q].z); xb.w = f2bf(xv[q].w);
        *(ushort4*)(xbf + (size_t)row * DIM + q * 256 + l * 4) = xb;
    }

    float acc[16];
#pragma unroll
    for (int u = 0; u < 16; ++u) {
        const float* wr_ = WT + (size_t)u * DIM + l * 4;
        float s = 0.f;
#pragma unroll
        for (int q = 0; q < 4; ++q) {
            float4 wv = *(const float4*)(wr_ + q * 256);
            s += xv[q].x * wv.x + xv[q].y * wv.y + xv[q].z * wv.z + xv[q].w * wv.w;
        }
        acc[u] = s;
    }

    // transpose-reduce: red[w][lane][u]; re-read column u, chunk c
#pragma unroll
    for (int u = 0; u < 16; ++u) red[w][l][u] = acc[u];
    asm volatile("s_waitcnt lgkmcnt(0)" ::: "memory");
    const int c = l >> 4, u = l & 15;
    float v = 0.f;
#pragma unroll
    for (int i = 0; i < 16; ++i) v += red[w][c * 16 + i][u];
    v += __shfl_xor(v, 16, 64);
    v += __shfl_xor(v, 32, 64);
    // lanes 0..15 hold totals for output u (replicated on upper lanes)

    const int e  = l & 7;
    float ag = __shfl(v, e, 64);
    float an = __shfl(v, e + 8, 64);
    float sp = (an > 0.f) ? (an + log1pf(expf(-an))) : log1pf(expf(an));
    float H  = ag + noise[e] * sp;       // lane e<8 holds H[e] (replicated mod 8)

    float Hh[8];
#pragma unroll
    for (int k = 0; k < 8; ++k) Hh[k] = __shfl(H, k, 64);
    if (l == 0) {
        int e0 = 0; float v0 = Hh[0];
#pragma unroll
        for (int k = 1; k < 8; ++k) if (Hh[k] > v0) { v0 = Hh[k]; e0 = k; }
        int e1 = -1; float v1 = 0.f;
#pragma unroll
        for (int k = 0; k < 8; ++k)
            if (k != e0 && (e1 < 0 || Hh[k] > v1)) { v1 = Hh[k]; e1 = k; }
        float rr = expf(v1 - v0);
        float w0 = 1.f / (1.f + rr), w1 = 1.f - w0;
        int p0 = atomicAdd(&cnt[e0], 1);
        idxl[(size_t)e0 * NR + p0] = row;  wl[(size_t)e0 * NR + p0] = w0;
        int p1 = atomicAdd(&cnt[NE + e1], 1);
        idxl[(size_t)(NE + e1) * NR + p1] = row;  wl[(size_t)(NE + e1) * NR + p1] = w1;
    }
}

// ---------------- grouped expert GEMM, all buckets in one dispatch -----------
__global__ __launch_bounds__(256, 2)
void moe_gemm(const ushort* __restrict__ xbf, const ushort* __restrict__ WeT,
              const float* __restrict__ be, const int* __restrict__ cnt,
              const int* __restrict__ idxl, const float* __restrict__ wl,
              float* __restrict__ out, float* __restrict__ y1,
              int bucket0, int use_y1) {
    __shared__ ushort Al[2][BM][GBK];
    __shared__ ushort Bl[2][BM][GBK];

    const int q8 = gridDim.x >> 3;
    const int W  = (blockIdx.x & 7) * q8 + (blockIdx.x >> 3);
    const int bucket = bucket0 + (W >> 8);
    const int t  = (W >> 3) & 31;
    const int cT = W & 7;
    const int count = cnt[bucket];
    if (t * BM >= count) return;
    const int nrowsv = min(BM, count - t * BM);
    const int e  = bucket & 7;
    const int c0 = cT * BN;
    const int*   rows = idxl + (size_t)bucket * NR + t * BM;
    const float* wrow = wl   + (size_t)bucket * NR + t * BM;

    const int tid = threadIdx.x, wid = tid >> 6, lane = tid & 63;
    const int wr = (wid >> 1) * 64, wc = (wid & 1) * 64;
    const int l16 = lane & 15, lhi = lane >> 4;
    const int lr8 = lane >> 3, lc8 = lane & 7;
    const int chunkp = lc8 ^ lr8;

    const ushort* aptr[4];
    const ushort* bptr[4];
#pragma unroll
    for (int q = 0; q < 4; ++q) {
        int r  = wid * 32 + q * 8 + lr8;
        int gr = rows[min(r, nrowsv - 1)];
        aptr[q] = xbf + (size_t)gr * DIM + chunkp * 8;
        int c = c0 + wid * 32 + q * 8 + lr8;
        bptr[q] = WeT + ((size_t)(e * DIM + c)) * DIM + chunkp * 8;
    }

    f32x4 acc[4][4];
#pragma unroll
    for (int m = 0; m < 4; ++m)
#pragma unroll
        for (int n = 0; n < 4; ++n) { f32x4 z = {0.f, 0.f, 0.f, 0.f}; acc[m][n] = z; }

#pragma unroll
    for (int q = 0; q < 4; ++q) {
        gload16(aptr[q], &Al[0][wid * 32 + q * 8][0]);
        gload16(bptr[q], &Bl[0][wid * 32 + q * 8][0]);
    }

    for (int s = 0; s < DIM / GBK; ++s) {
        const int buf = s & 1;
        if (s + 1 < DIM / GBK) {
            const int nb = buf ^ 1, k0 = (s + 1) * GBK;
#pragma unroll
            for (int q = 0; q < 4; ++q) {
                gload16(aptr[q] + k0, &Al[nb][wid * 32 + q * 8][0]);
                gload16(bptr[q] + k0, &Bl[nb][wid * 32 + q * 8][0]);
            }
            asm volatile("s_waitcnt vmcnt(8)" ::: "memory");
        } else {
            asm volatile("s_waitcnt vmcnt(0)" ::: "memory");
        }
        __builtin_amdgcn_s_barrier();

        const ushort* Ab = &Al[buf][0][0];
        const ushort* Bb = &Bl[buf][0][0];
#pragma unroll
        for (int h = 0; h < 2; ++h) {
            bf16x8 af[4], bfr[4];
            const int chb = (h * 4 + lhi) ^ (l16 & 7);
#pragma unroll
            for (int m = 0; m < 4; ++m) {
                int rr = wr + m * 16 + l16;
                af[m] = *(const bf16x8*)(Ab + rr * GBK + chb * 8);
            }
#pragma unroll
            for (int n = 0; n < 4; ++n) {
                int rr = wc + n * 16 + l16;
                bfr[n] = *(const bf16x8*)(Bb + rr * GBK + chb * 8);
            }
#pragma unroll
            for (int m = 0; m < 4; ++m)
#pragma unroll
                for (int n = 0; n < 4; ++n)
                    acc[m][n] = __builtin_amdgcn_mfma_f32_16x16x32_bf16(af[m], bfr[n], acc[m][n], 0, 0, 0);
        }
        asm volatile("s_waitcnt lgkmcnt(0)" ::: "memory");
        __builtin_amdgcn_s_barrier();
    }

    float* dst = (bucket >= NE && use_y1) ? y1 : out;
    const bool accum = (bucket >= NE) && !use_y1;
    float bev[4];
#pragma unroll
    for (int n = 0; n < 4; ++n) bev[n] = be[(size_t)e * DIM + c0 + wc + n * 16 + l16];
#pragma unroll
    for (int m = 0; m < 4; ++m) {
#pragma unroll
        for (int r = 0; r < 4; ++r) {
            int rl = wr + m * 16 + lhi * 4 + r;
            if (rl < nrowsv) {
                int   gr = rows[rl];
                float w  = wrow[rl];
                float* op = dst + (size_t)gr * DIM + c0 + wc;
#pragma unroll
                for (int n = 0; n < 4; ++n) {
                    float v   = w * (acc[m][n][r] + bev[n]);
                    int   col = n * 16 + l16;
                    if (accum) op[col] += v; else op[col] = v;
                }
            }
        }
    }
}

// ---------------- out += Y1 --------------------------------------------------
__global__ __launch_bounds__(256)
void add_out(float* __restrict__ out, const float* __restrict__ y1) {
    const int n4 = NR * DIM / 4;
    for (int i = blockIdx.x * blockDim.x + threadIdx.x; i < n4; i += gridDim.x * blockDim.x) {
        float4 a = ((float4*)out)[i];
        float4 b = ((const float4*)y1)[i];
        a.x += b.x; a.y += b.y; a.z += b.z; a.w += b.w;
        ((float4*)out)[i] = a;
    }
}

extern "C" void kernel_launch(void* const* d_in, const int* in_sizes, int n_in,
                              void* d_out, int out_size, void* d_ws, size_t ws_size,
                              hipStream_t stream) {
    const float* x     = (const float*)d_in[0];
    const float* noise = (const float*)d_in[1];
    const float* Wg    = (const float*)d_in[2];
    const float* Wn    = (const float*)d_in[3];
    const float* We    = (const float*)d_in[4];
    const float* be    = (const float*)d_in[5];
    float* out = (float*)d_out;

    char* w = (char*)d_ws;
    size_t off = 256;
    int*   cnt  = (int*)w;
    int*   idxl = (int*)(w + off);  off += (size_t)2 * NE * NR * 4;
    float* wl   = (float*)(w + off); off += (size_t)2 * NE * NR * 4;
    off = (off + 255) & ~(size_t)255;
    float*  WT  = (float*)(w + off);  off += (size_t)16 * DIM * 4;        // 64 KB
    ushort* xbf = (ushort*)(w + off); off += (size_t)NR * DIM * 2;        // 8 MB
    ushort* WeT = (ushort*)(w + off); off += (size_t)NE * DIM * DIM * 2;  // 16 MB
    float*  y1  = (float*)(w + off);
    size_t need_y1 = off + (size_t)NR * DIM * 4;                          // +16 MB
    const int use_y1 = (ws_size >= need_y1) ? 1 : 0;

    conv_we<<<NE * 16 * 16, 256, 0, stream>>>(We, WeT, Wg, Wn, WT, cnt);
    gate_v4<<<NR / 4, 256, 0, stream>>>(x, noise, WT, xbf, cnt, idxl, wl);

    if (use_y1) {
        moe_gemm<<<16 * 32 * 8, 256, 0, stream>>>(xbf, WeT, be, cnt, idxl, wl, out, y1, 0, 1);
        add_out<<<2048, 256, 0, stream>>>(out, y1);
    } else {
        moe_gemm<<<8 * 32 * 8, 256, 0, stream>>>(xbf, WeT, be, cnt, idxl, wl, out, nullptr, 0, 0);
        moe_gemm<<<8 * 32 * 8, 256, 0, stream>>>(xbf, WeT, be, cnt, idxl, wl, out, nullptr, 8, 0);
    }
}

// Round 5
// 85.559 us; speedup vs baseline: 1.9827x; 1.9827x over previous
//
#include <hip/hip_runtime.h>
#include <hip/hip_bf16.h>
#include <stdint.h>

#define NR   4096
#define DIM  1024
#define NE   8
#define BM   128
#define BN   128
#define GBK  64

typedef __attribute__((ext_vector_type(8))) short  bf16x8;
typedef __attribute__((ext_vector_type(8))) ushort u16x8;
typedef __attribute__((ext_vector_type(4))) float  f32x4;

__device__ __forceinline__ ushort f2bf(float f) {
    union { __hip_bfloat16 h; ushort u; } cv;
    cv.h = __float2bfloat16(f);   // RNE
    return cv.u;
}

__device__ __forceinline__ void gload16(const void* g, void* l) {
    __builtin_amdgcn_global_load_lds(
        (const __attribute__((address_space(1))) unsigned int*)g,
        (__attribute__((address_space(3))) unsigned int*)l, 16, 0, 0);
}

// ---------------- convert+transpose We: [e][k][c] f32 -> WeT [e][c][k] bf16 ---
// blocks 0/1 additionally transpose Wg/Wn -> WT[16][1024] f32
__global__ __launch_bounds__(256)
void conv_we(const float* __restrict__ We, ushort* __restrict__ WeT,
             const float* __restrict__ Wg, const float* __restrict__ Wn,
             float* __restrict__ WT) {
    if (blockIdx.x < 2) {
        const float* Ws = (blockIdx.x == 0) ? Wg : Wn;
        float* dstT = WT + (size_t)blockIdx.x * 8 * DIM;
#pragma unroll
        for (int i = 0; i < 8; ++i) {
            int idx = i * 256 + threadIdx.x;     // 2048 float4 units
            int k = idx >> 1, e4 = (idx & 1) * 4;
            float4 v = *(const float4*)(Ws + (size_t)k * NE + e4);
            dstT[(size_t)(e4 + 0) * DIM + k] = v.x;
            dstT[(size_t)(e4 + 1) * DIM + k] = v.y;
            dstT[(size_t)(e4 + 2) * DIM + k] = v.z;
            dstT[(size_t)(e4 + 3) * DIM + k] = v.w;
        }
    }
    const int b  = blockIdx.x;              // e*256 + kt*16 + ct
    const int e  = b >> 8, kt = (b >> 4) & 15, ct = b & 15;
    __shared__ float T[64][68];
    const float* src = We + ((size_t)e * DIM + (size_t)kt * 64) * DIM + ct * 64;
#pragma unroll
    for (int j = 0; j < 4; ++j) {
        int idx = threadIdx.x + j * 256;
        int r = idx >> 4, c4 = idx & 15;
        float4 v = *(const float4*)(src + (size_t)r * DIM + c4 * 4);
        *(float4*)&T[r][c4 * 4] = v;
    }
    __syncthreads();
    ushort* dst = WeT + ((size_t)e * DIM + (size_t)ct * 64) * DIM + kt * 64;
#pragma unroll
    for (int j = 0; j < 2; ++j) {
        int u = threadIdx.x + j * 256;
        int c = u >> 3, ch = u & 7;
        ushort tmp[8];
#pragma unroll
        for (int q = 0; q < 8; ++q) tmp[q] = f2bf(T[ch * 8 + q][c]);
        *(u16x8*)(dst + (size_t)c * DIM + ch * 8) = *(u16x8*)tmp;
    }
}

// ---------------- gating v5: one wave per row, NO atomics --------------------
// writes eid[row] = e0 | (e1<<8) and wpair[row] = (w0, w1); also emits xbf.
__global__ __launch_bounds__(256, 4)
void gate_v5(const float* __restrict__ x, const float* __restrict__ noise,
             const float* __restrict__ WT, ushort* __restrict__ xbf,
             uint32_t* __restrict__ eid, float2* __restrict__ wpair) {
    __shared__ float red[4][64][17];
    const int tid = threadIdx.x, w = tid >> 6, l = tid & 63;
    const int row = blockIdx.x * 4 + w;
    const float* xr = x + (size_t)row * DIM;

    float4 xv[4];
#pragma unroll
    for (int q = 0; q < 4; ++q) xv[q] = *(const float4*)(xr + q * 256 + l * 4);
#pragma unroll
    for (int q = 0; q < 4; ++q) {
        ushort4 xb;
        xb.x = f2bf(xv[q].x); xb.y = f2bf(xv[q].y);
        xb.z = f2bf(xv[q].z); xb.w = f2bf(xv[q].w);
        *(ushort4*)(xbf + (size_t)row * DIM + q * 256 + l * 4) = xb;
    }

    float acc[16];
#pragma unroll
    for (int u = 0; u < 16; ++u) {
        const float* wr_ = WT + (size_t)u * DIM + l * 4;
        float s = 0.f;
#pragma unroll
        for (int q = 0; q < 4; ++q) {
            float4 wv = *(const float4*)(wr_ + q * 256);
            s += xv[q].x * wv.x + xv[q].y * wv.y + xv[q].z * wv.z + xv[q].w * wv.w;
        }
        acc[u] = s;
    }

#pragma unroll
    for (int u = 0; u < 16; ++u) red[w][l][u] = acc[u];
    asm volatile("s_waitcnt lgkmcnt(0)" ::: "memory");
    const int c = l >> 4, u = l & 15;
    float v = 0.f;
#pragma unroll
    for (int i = 0; i < 16; ++i) v += red[w][c * 16 + i][u];
    v += __shfl_xor(v, 16, 64);
    v += __shfl_xor(v, 32, 64);

    const int e  = l & 7;
    float ag = __shfl(v, e, 64);
    float an = __shfl(v, e + 8, 64);
    float sp = (an > 0.f) ? (an + log1pf(expf(-an))) : log1pf(expf(an));
    float H  = ag + noise[e] * sp;

    float Hh[8];
#pragma unroll
    for (int k = 0; k < 8; ++k) Hh[k] = __shfl(H, k, 64);
    if (l == 0) {
        int e0 = 0; float v0 = Hh[0];
#pragma unroll
        for (int k = 1; k < 8; ++k) if (Hh[k] > v0) { v0 = Hh[k]; e0 = k; }
        int e1 = -1; float v1 = 0.f;
#pragma unroll
        for (int k = 0; k < 8; ++k)
            if (k != e0 && (e1 < 0 || Hh[k] > v1)) { v1 = Hh[k]; e1 = k; }
        float rr = expf(v1 - v0);
        float w0 = 1.f / (1.f + rr), w1 = 1.f - w0;
        eid[row]   = (uint32_t)e0 | ((uint32_t)e1 << 8);
        float2 wp; wp.x = w0; wp.y = w1;
        wpair[row] = wp;
    }
}

// ---------------- bucket build: deterministic compaction, no global atomics --
// 16 blocks (one per bucket) x 1024 threads; row-order-stable within bucket.
__global__ __launch_bounds__(1024)
void bucket_build(const uint32_t* __restrict__ eid, const float2* __restrict__ wpair,
                  int* __restrict__ cnt, int* __restrict__ idxl, float* __restrict__ wl) {
    const int bucket = blockIdx.x;          // 0..15
    const int slot = bucket >> 3, ex = bucket & 7;
    __shared__ int base;
    __shared__ int wsum[16];
    if (threadIdx.x == 0) base = 0;
    const int wid = threadIdx.x >> 6, lane = threadIdx.x & 63;
    int* bidx = idxl + (size_t)bucket * NR;
    float* bwl = wl + (size_t)bucket * NR;

    for (int c0 = 0; c0 < NR; c0 += 1024) {
        const int row = c0 + threadIdx.x;
        const uint32_t em = eid[row];
        const int e = slot ? (int)((em >> 8) & 255u) : (int)(em & 255u);
        const bool m = (e == ex);
        const unsigned long long bal = __ballot(m);
        if (lane == 0) wsum[wid] = __popcll(bal);
        __syncthreads();
        int wbase = base;
        for (int i = 0; i < wid; ++i) wbase += wsum[i];
        const int pos = wbase + __popcll(bal & ((1ull << lane) - 1ull));
        if (m) {
            bidx[pos] = row;
            float2 wp = wpair[row];
            bwl[pos]  = slot ? wp.y : wp.x;
        }
        __syncthreads();
        if (threadIdx.x == 0) {
            int s = 0;
#pragma unroll
            for (int i = 0; i < 16; ++i) s += wsum[i];
            base += s;
        }
        __syncthreads();
    }
    if (threadIdx.x == 0) cnt[bucket] = base;
}

// ---------------- grouped expert GEMM, all buckets in one dispatch -----------
__global__ __launch_bounds__(256, 2)
void moe_gemm(const ushort* __restrict__ xbf, const ushort* __restrict__ WeT,
              const float* __restrict__ be, const int* __restrict__ cnt,
              const int* __restrict__ idxl, const float* __restrict__ wl,
              float* __restrict__ out, float* __restrict__ y1,
              int bucket0, int use_y1) {
    __shared__ ushort Al[2][BM][GBK];
    __shared__ ushort Bl[2][BM][GBK];

    const int q8 = gridDim.x >> 3;
    const int W  = (blockIdx.x & 7) * q8 + (blockIdx.x >> 3);
    const int bucket = bucket0 + (W >> 8);
    const int t  = (W >> 3) & 31;
    const int cT = W & 7;
    const int count = cnt[bucket];
    if (t * BM >= count) return;
    const int nrowsv = min(BM, count - t * BM);
    const int e  = bucket & 7;
    const int c0 = cT * BN;
    const int*   rows = idxl + (size_t)bucket * NR + t * BM;
    const float* wrow = wl   + (size_t)bucket * NR + t * BM;

    const int tid = threadIdx.x, wid = tid >> 6, lane = tid & 63;
    const int wr = (wid >> 1) * 64, wc = (wid & 1) * 64;
    const int l16 = lane & 15, lhi = lane >> 4;
    const int lr8 = lane >> 3, lc8 = lane & 7;
    const int chunkp = lc8 ^ lr8;

    const ushort* aptr[4];
    const ushort* bptr[4];
#pragma unroll
    for (int q = 0; q < 4; ++q) {
        int r  = wid * 32 + q * 8 + lr8;
        int gr = rows[min(r, nrowsv - 1)];
        aptr[q] = xbf + (size_t)gr * DIM + chunkp * 8;
        int c = c0 + wid * 32 + q * 8 + lr8;
        bptr[q] = WeT + ((size_t)(e * DIM + c)) * DIM + chunkp * 8;
    }

    f32x4 acc[4][4];
#pragma unroll
    for (int m = 0; m < 4; ++m)
#pragma unroll
        for (int n = 0; n < 4; ++n) { f32x4 z = {0.f, 0.f, 0.f, 0.f}; acc[m][n] = z; }

#pragma unroll
    for (int q = 0; q < 4; ++q) {
        gload16(aptr[q], &Al[0][wid * 32 + q * 8][0]);
        gload16(bptr[q], &Bl[0][wid * 32 + q * 8][0]);
    }

    for (int s = 0; s < DIM / GBK; ++s) {
        const int buf = s & 1;
        if (s + 1 < DIM / GBK) {
            const int nb = buf ^ 1, k0 = (s + 1) * GBK;
#pragma unroll
            for (int q = 0; q < 4; ++q) {
                gload16(aptr[q] + k0, &Al[nb][wid * 32 + q * 8][0]);
                gload16(bptr[q] + k0, &Bl[nb][wid * 32 + q * 8][0]);
            }
            asm volatile("s_waitcnt vmcnt(8)" ::: "memory");
        } else {
            asm volatile("s_waitcnt vmcnt(0)" ::: "memory");
        }
        __builtin_amdgcn_s_barrier();

        const ushort* Ab = &Al[buf][0][0];
        const ushort* Bb = &Bl[buf][0][0];
#pragma unroll
        for (int h = 0; h < 2; ++h) {
            bf16x8 af[4], bfr[4];
            const int chb = (h * 4 + lhi) ^ (l16 & 7);
#pragma unroll
            for (int m = 0; m < 4; ++m) {
                int rr = wr + m * 16 + l16;
                af[m] = *(const bf16x8*)(Ab + rr * GBK + chb * 8);
            }
#pragma unroll
            for (int n = 0; n < 4; ++n) {
                int rr = wc + n * 16 + l16;
                bfr[n] = *(const bf16x8*)(Bb + rr * GBK + chb * 8);
            }
#pragma unroll
            for (int m = 0; m < 4; ++m)
#pragma unroll
                for (int n = 0; n < 4; ++n)
                    acc[m][n] = __builtin_amdgcn_mfma_f32_16x16x32_bf16(af[m], bfr[n], acc[m][n], 0, 0, 0);
        }
        asm volatile("s_waitcnt lgkmcnt(0)" ::: "memory");
        __builtin_amdgcn_s_barrier();
    }

    float* dst = (bucket >= NE && use_y1) ? y1 : out;
    const bool accum = (bucket >= NE) && !use_y1;
    float bev[4];
#pragma unroll
    for (int n = 0; n < 4; ++n) bev[n] = be[(size_t)e * DIM + c0 + wc + n * 16 + l16];
#pragma unroll
    for (int m = 0; m < 4; ++m) {
#pragma unroll
        for (int r = 0; r < 4; ++r) {
            int rl = wr + m * 16 + lhi * 4 + r;
            if (rl < nrowsv) {
                int   gr = rows[rl];
                float w  = wrow[rl];
                float* op = dst + (size_t)gr * DIM + c0 + wc;
#pragma unroll
                for (int n = 0; n < 4; ++n) {
                    float v   = w * (acc[m][n][r] + bev[n]);
                    int   col = n * 16 + l16;
                    if (accum) op[col] += v; else op[col] = v;
                }
            }
        }
    }
}

// ---------------- out += Y1 --------------------------------------------------
__global__ __launch_bounds__(256)
void add_out(float* __restrict__ out, const float* __restrict__ y1) {
    const int n4 = NR * DIM / 4;
    for (int i = blockIdx.x * blockDim.x + threadIdx.x; i < n4; i += gridDim.x * blockDim.x) {
        float4 a = ((float4*)out)[i];
        float4 b = ((const float4*)y1)[i];
        a.x += b.x; a.y += b.y; a.z += b.z; a.w += b.w;
        ((float4*)out)[i] = a;
    }
}

extern "C" void kernel_launch(void* const* d_in, const int* in_sizes, int n_in,
                              void* d_out, int out_size, void* d_ws, size_t ws_size,
                              hipStream_t stream) {
    const float* x     = (const float*)d_in[0];
    const float* noise = (const float*)d_in[1];
    const float* Wg    = (const float*)d_in[2];
    const float* Wn    = (const float*)d_in[3];
    const float* We    = (const float*)d_in[4];
    const float* be    = (const float*)d_in[5];
    float* out = (float*)d_out;

    char* w = (char*)d_ws;
    size_t off = 256;
    int*      cnt   = (int*)w;
    int*      idxl  = (int*)(w + off);     off += (size_t)2 * NE * NR * 4;   // 256 KB
    float*    wl    = (float*)(w + off);   off += (size_t)2 * NE * NR * 4;   // 256 KB
    uint32_t* eid   = (uint32_t*)(w + off); off += (size_t)NR * 4;           // 16 KB
    float2*   wpair = (float2*)(w + off);  off += (size_t)NR * 8;            // 32 KB
    off = (off + 255) & ~(size_t)255;
    float*  WT  = (float*)(w + off);  off += (size_t)16 * DIM * 4;           // 64 KB
    ushort* xbf = (ushort*)(w + off); off += (size_t)NR * DIM * 2;           // 8 MB
    ushort* WeT = (ushort*)(w + off); off += (size_t)NE * DIM * DIM * 2;     // 16 MB
    float*  y1  = (float*)(w + off);
    size_t need_y1 = off + (size_t)NR * DIM * 4;                             // +16 MB
    const int use_y1 = (ws_size >= need_y1) ? 1 : 0;

    conv_we<<<NE * 16 * 16, 256, 0, stream>>>(We, WeT, Wg, Wn, WT);
    gate_v5<<<NR / 4, 256, 0, stream>>>(x, noise, WT, xbf, eid, wpair);
    bucket_build<<<16, 1024, 0, stream>>>(eid, wpair, cnt, idxl, wl);

    if (use_y1) {
        moe_gemm<<<16 * 32 * 8, 256, 0, stream>>>(xbf, WeT, be, cnt, idxl, wl, out, y1, 0, 1);
        add_out<<<2048, 256, 0, stream>>>(out, y1);
    } else {
        moe_gemm<<<8 * 32 * 8, 256, 0, stream>>>(xbf, WeT, be, cnt, idxl, wl, out, nullptr, 0, 0);
        moe_gemm<<<8 * 32 * 8, 256, 0, stream>>>(xbf, WeT, be, cnt, idxl, wl, out, nullptr, 8, 0);
    }
}